// Round 1
// baseline (4766.744 us; speedup 1.0000x reference)
//
#include <hip/hip_runtime.h>
#include <hip/hip_bf16.h>

constexpr int N_NODES = 100000;
constexpr int N_REL   = 3;
constexpr int N_EDGE  = 1600000;

// ---------------- graph preprocessing ----------------

__global__ void degree_kernel(const int* __restrict__ src, const int* __restrict__ dst,
                              int* __restrict__ deg_out, int* __restrict__ deg_in) {
  int tid = blockIdx.x * blockDim.x + threadIdx.x;
  if (tid >= N_REL * N_EDGE) return;
  int r = tid / N_EDGE;
  atomicAdd(&deg_out[r * N_NODES + src[tid]], 1);
  atomicAdd(&deg_in [r * N_NODES + dst[tid]], 1);
}

__global__ void inv_kernel(const int* __restrict__ deg_out, const int* __restrict__ deg_in,
                           float* __restrict__ inv_out, float* __restrict__ inv_in) {
  int i = blockIdx.x * blockDim.x + threadIdx.x;
  if (i >= N_REL * N_NODES) return;
  inv_out[i] = rsqrtf(fmaxf((float)deg_out[i], 1.0f));
  inv_in[i]  = rsqrtf(fmaxf((float)deg_in[i],  1.0f));
}

// one block per relation; exclusive scan of in-degrees -> CSR row offsets
__global__ void scan_kernel(const int* __restrict__ deg_in, int* __restrict__ row_off,
                            int* __restrict__ cursor) {
  int r = blockIdx.x;
  const int* d = deg_in + r * N_NODES;
  int* ro  = row_off + r * (N_NODES + 1);
  int* cur = cursor  + r * N_NODES;
  __shared__ int smem[1024];
  __shared__ int sbase;
  if (threadIdx.x == 0) sbase = 0;
  __syncthreads();
  for (int base = 0; base < N_NODES; base += 1024) {
    int i = base + (int)threadIdx.x;
    int v = (i < N_NODES) ? d[i] : 0;
    smem[threadIdx.x] = v;
    __syncthreads();
    for (int off = 1; off < 1024; off <<= 1) {
      int t = (threadIdx.x >= off) ? smem[threadIdx.x - off] : 0;
      __syncthreads();
      smem[threadIdx.x] += t;
      __syncthreads();
    }
    int excl = smem[threadIdx.x] - v;
    int myb = sbase;                 // stable: write is behind the sync below
    if (i < N_NODES) { ro[i] = myb + excl; cur[i] = myb + excl; }
    int tot = smem[1023];
    __syncthreads();
    if (threadIdx.x == 0) sbase += tot;
    __syncthreads();
  }
  if (threadIdx.x == 0) ro[N_NODES] = sbase;   // == N_EDGE
}

__global__ void bucket_kernel(const int* __restrict__ src, const int* __restrict__ dst,
                              const float* __restrict__ inv_out, const float* __restrict__ inv_in,
                              int* __restrict__ cursor, int* __restrict__ sorted_src,
                              float* __restrict__ sorted_coef) {
  int tid = blockIdx.x * blockDim.x + threadIdx.x;
  if (tid >= N_REL * N_EDGE) return;
  int r = tid / N_EDGE;
  int s = src[tid], d = dst[tid];
  int pos = atomicAdd(&cursor[r * N_NODES + d], 1);
  size_t o = (size_t)r * N_EDGE + pos;
  sorted_src[o]  = s;
  sorted_coef[o] = inv_out[r * N_NODES + s] * inv_in[r * N_NODES + d];
}

// ---------------- per-layer kernels ----------------

// Y[n][r][DO] = h[n][:] @ W[r][:][:]   (K=128 always)
template<int DO>
__launch_bounds__(256)
__global__ void gemm_kernel(const float* __restrict__ A, const float* __restrict__ W,
                            float* __restrict__ Y) {
  constexpr int TN = DO / 16;      // cols per thread (8 or 4)
  constexpr int LD = 3 * DO;       // Y row stride
  int r  = blockIdx.y;
  int m0 = blockIdx.x * 128;
  const float* Wr = W + (size_t)r * 128 * DO;
  int tid = threadIdx.x;
  int tx = tid & 15;               // col group
  int ty = tid >> 4;               // row group
  __shared__ float As[128][17];    // [row][kk], +1 pad breaks bank conflicts
  __shared__ float Bs[16][DO];     // [kk][col]
  float acc[8][TN];
  #pragma unroll
  for (int i = 0; i < 8; i++)
    #pragma unroll
    for (int j = 0; j < TN; j++) acc[i][j] = 0.f;

  for (int k0 = 0; k0 < 128; k0 += 16) {
    #pragma unroll
    for (int idx = tid; idx < 128 * 16; idx += 256) {
      int row = idx >> 4, kk = idx & 15;
      float v = 0.f;
      if (m0 + row < N_NODES) v = A[(size_t)(m0 + row) * 128 + k0 + kk];
      As[row][kk] = v;
    }
    #pragma unroll
    for (int idx = tid; idx < 16 * DO; idx += 256) {
      int kk = idx / DO, c = idx % DO;
      Bs[kk][c] = Wr[(size_t)(k0 + kk) * DO + c];
    }
    __syncthreads();
    #pragma unroll
    for (int kk = 0; kk < 16; kk++) {
      float a[8], bv[TN];
      #pragma unroll
      for (int i = 0; i < 8; i++) a[i] = As[ty * 8 + i][kk];
      #pragma unroll
      for (int j = 0; j < TN; j++) bv[j] = Bs[kk][tx * TN + j];
      #pragma unroll
      for (int i = 0; i < 8; i++)
        #pragma unroll
        for (int j = 0; j < TN; j++) acc[i][j] = fmaf(a[i], bv[j], acc[i][j]);
    }
    __syncthreads();
  }
  #pragma unroll
  for (int i = 0; i < 8; i++) {
    int row = m0 + ty * 8 + i;
    if (row < N_NODES) {
      float* yp = Y + (size_t)row * LD + r * DO + tx * TN;
      #pragma unroll
      for (int j = 0; j < TN; j += 4) {
        *(float4*)(yp + j) = make_float4(acc[i][j], acc[i][j+1], acc[i][j+2], acc[i][j+3]);
      }
    }
  }
}

// one wave per node: out[n][:] = sum_r ( sum_{e in CSR_r(n)} coef_e * Y[src_e][r][:] ) + sum_r b[r][:]
template<int DO>
__launch_bounds__(256)
__global__ void agg_kernel(const float* __restrict__ Y, const int* __restrict__ sorted_src,
                           const float* __restrict__ sorted_coef, const int* __restrict__ row_off,
                           const float* __restrict__ b, float* __restrict__ out, int apply_relu) {
  constexpr int J  = DO / 64;
  constexpr int LD = 3 * DO;
  int node = blockIdx.x * 4 + ((int)threadIdx.x >> 6);
  int lane = (int)threadIdx.x & 63;
  if (node >= N_NODES) return;
  float acc[J];
  #pragma unroll
  for (int j = 0; j < J; j++)
    acc[j] = b[0 * DO + lane + 64 * j] + b[1 * DO + lane + 64 * j] + b[2 * DO + lane + 64 * j];
  #pragma unroll
  for (int r = 0; r < N_REL; r++) {
    const int* ro = row_off + r * (N_NODES + 1);
    int beg = ro[node], end = ro[node + 1];
    const int*   ss = sorted_src  + (size_t)r * N_EDGE;
    const float* sc = sorted_coef + (size_t)r * N_EDGE;
    const float* Yr = Y + r * DO;
    for (int e = beg; e < end; e++) {
      int s   = ss[e];
      float c = sc[e];
      const float* rowp = Yr + (size_t)s * LD;
      #pragma unroll
      for (int j = 0; j < J; j++) acc[j] = fmaf(c, rowp[lane + 64 * j], acc[j]);
    }
  }
  float* o = out + (size_t)node * DO;
  #pragma unroll
  for (int j = 0; j < J; j++) {
    float v = acc[j];
    if (apply_relu) v = fmaxf(v, 0.f);
    o[lane + 64 * j] = v;
  }
}

// ---------------- launch ----------------

extern "C" void kernel_launch(void* const* d_in, const int* in_sizes, int n_in,
                              void* d_out, int out_size, void* d_ws, size_t ws_size,
                              hipStream_t stream) {
  const float* x   = (const float*)d_in[0];
  const int*   src = (const int*)d_in[1];
  const int*   dst = (const int*)d_in[2];
  const float* Wl[6]; const float* bl[6];
  for (int i = 0; i < 6; i++) { Wl[i] = (const float*)d_in[3 + 2*i]; bl[i] = (const float*)d_in[4 + 2*i]; }

  char* ws = (char*)d_ws;
  size_t off = 0;
  auto take = [&](size_t bytes) -> char* {
    char* p = ws + off;
    off = (off + bytes + 255) & ~(size_t)255;
    return p;
  };
  float* h       = (float*)take((size_t)N_NODES * 128 * 4);
  float* Y       = (float*)take((size_t)N_NODES * 384 * 4);
  int*   deg     = (int*)  take((size_t)2 * N_REL * N_NODES * 4);   // deg_out | deg_in
  int*   deg_out = deg;
  int*   deg_in  = deg + N_REL * N_NODES;
  float* inv_out = (float*)take((size_t)N_REL * N_NODES * 4);
  float* inv_in  = (float*)take((size_t)N_REL * N_NODES * 4);
  int*   row_off = (int*)  take((size_t)N_REL * (N_NODES + 1) * 4);
  int*   cursor  = (int*)  take((size_t)N_REL * N_NODES * 4);
  int*   s_src   = (int*)  take((size_t)N_REL * N_EDGE * 4);
  float* s_coef  = (float*)take((size_t)N_REL * N_EDGE * 4);
  (void)ws_size; (void)in_sizes; (void)n_in; (void)out_size;

  hipMemsetAsync(deg, 0, (size_t)2 * N_REL * N_NODES * 4, stream);

  const int eblocks = (N_REL * N_EDGE + 255) / 256;
  const int nblocks = (N_REL * N_NODES + 255) / 256;
  degree_kernel<<<eblocks, 256, 0, stream>>>(src, dst, deg_out, deg_in);
  inv_kernel<<<nblocks, 256, 0, stream>>>(deg_out, deg_in, inv_out, inv_in);
  scan_kernel<<<N_REL, 1024, 0, stream>>>(deg_in, row_off, cursor);
  bucket_kernel<<<eblocks, 256, 0, stream>>>(src, dst, inv_out, inv_in, cursor, s_src, s_coef);

  const int mtiles = (N_NODES + 127) / 128;
  const int agg_blocks = (N_NODES + 3) / 4;
  const float* h_in = x;
  for (int L = 0; L < 6; L++) {
    if (L < 5) {
      gemm_kernel<128><<<dim3(mtiles, 3), 256, 0, stream>>>(h_in, Wl[L], Y);
      agg_kernel<128><<<agg_blocks, 256, 0, stream>>>(Y, s_src, s_coef, row_off, bl[L], h, 1);
      h_in = h;
    } else {
      gemm_kernel<64><<<dim3(mtiles, 3), 256, 0, stream>>>(h_in, Wl[L], Y);
      agg_kernel<64><<<agg_blocks, 256, 0, stream>>>(Y, s_src, s_coef, row_off, bl[L], (float*)d_out, 0);
    }
  }
}

// Round 2
// 4093.333 us; speedup vs baseline: 1.1645x; 1.1645x over previous
//
#include <hip/hip_runtime.h>
#include <hip/hip_bf16.h>

constexpr int N_NODES = 100000;
constexpr int N_REL   = 3;
constexpr int N_EDGE  = 1600000;

// ---------------- graph preprocessing ----------------

__global__ void degree_kernel(const int* __restrict__ src, const int* __restrict__ dst,
                              int* __restrict__ deg_out, int* __restrict__ deg_in) {
  int tid = blockIdx.x * blockDim.x + threadIdx.x;
  if (tid >= N_REL * N_EDGE) return;
  int r = tid / N_EDGE;
  atomicAdd(&deg_out[r * N_NODES + src[tid]], 1);
  atomicAdd(&deg_in [r * N_NODES + dst[tid]], 1);
}

__global__ void inv_kernel(const int* __restrict__ deg_out, const int* __restrict__ deg_in,
                           float* __restrict__ inv_out, float* __restrict__ inv_in) {
  int i = blockIdx.x * blockDim.x + threadIdx.x;
  if (i >= N_REL * N_NODES) return;
  inv_out[i] = rsqrtf(fmaxf((float)deg_out[i], 1.0f));
  inv_in[i]  = rsqrtf(fmaxf((float)deg_in[i],  1.0f));
}

// one block per relation; exclusive scan of in-degrees -> CSR row offsets
__global__ void scan_kernel(const int* __restrict__ deg_in, int* __restrict__ row_off,
                            int* __restrict__ cursor) {
  int r = blockIdx.x;
  const int* d = deg_in + r * N_NODES;
  int* ro  = row_off + r * (N_NODES + 1);
  int* cur = cursor  + r * N_NODES;
  __shared__ int smem[1024];
  __shared__ int sbase;
  if (threadIdx.x == 0) sbase = 0;
  __syncthreads();
  for (int base = 0; base < N_NODES; base += 1024) {
    int i = base + (int)threadIdx.x;
    int v = (i < N_NODES) ? d[i] : 0;
    smem[threadIdx.x] = v;
    __syncthreads();
    for (int off = 1; off < 1024; off <<= 1) {
      int t = (threadIdx.x >= off) ? smem[threadIdx.x - off] : 0;
      __syncthreads();
      smem[threadIdx.x] += t;
      __syncthreads();
    }
    int excl = smem[threadIdx.x] - v;
    int myb = sbase;
    if (i < N_NODES) { ro[i] = myb + excl; cur[i] = myb + excl; }
    int tot = smem[1023];
    __syncthreads();
    if (threadIdx.x == 0) sbase += tot;
    __syncthreads();
  }
  if (threadIdx.x == 0) ro[N_NODES] = sbase;   // == N_EDGE
}

// write interleaved (src_as_float, coef) per sorted edge slot
__global__ void bucket_kernel(const int* __restrict__ src, const int* __restrict__ dst,
                              const float* __restrict__ inv_out, const float* __restrict__ inv_in,
                              int* __restrict__ cursor, float2* __restrict__ sorted_sc) {
  int tid = blockIdx.x * blockDim.x + threadIdx.x;
  if (tid >= N_REL * N_EDGE) return;
  int r = tid / N_EDGE;
  int s = src[tid], d = dst[tid];
  int pos = atomicAdd(&cursor[r * N_NODES + d], 1);
  size_t o = (size_t)r * N_EDGE + pos;
  float coef = inv_out[r * N_NODES + s] * inv_in[r * N_NODES + d];
  sorted_sc[o] = make_float2(__int_as_float(s), coef);
}

// ---------------- per-layer kernels ----------------

// Y[n][r][DO] = h[n][:] @ W[r][:][:]   (K=128 always)
template<int DO>
__launch_bounds__(256)
__global__ void gemm_kernel(const float* __restrict__ A, const float* __restrict__ W,
                            float* __restrict__ Y) {
  constexpr int TN = DO / 16;      // cols per thread (8 or 4)
  constexpr int LD = 3 * DO;       // Y row stride
  int r  = blockIdx.y;
  int m0 = blockIdx.x * 128;
  const float* Wr = W + (size_t)r * 128 * DO;
  int tid = threadIdx.x;
  int tx = tid & 15;               // col group
  int ty = tid >> 4;               // row group
  __shared__ float As[128][17];    // [row][kk], +1 pad breaks bank conflicts
  __shared__ float Bs[16][DO];     // [kk][col]
  float acc[8][TN];
  #pragma unroll
  for (int i = 0; i < 8; i++)
    #pragma unroll
    for (int j = 0; j < TN; j++) acc[i][j] = 0.f;

  for (int k0 = 0; k0 < 128; k0 += 16) {
    #pragma unroll
    for (int idx = tid; idx < 128 * 16; idx += 256) {
      int row = idx >> 4, kk = idx & 15;
      float v = 0.f;
      if (m0 + row < N_NODES) v = A[(size_t)(m0 + row) * 128 + k0 + kk];
      As[row][kk] = v;
    }
    #pragma unroll
    for (int idx = tid; idx < 16 * DO; idx += 256) {
      int kk = idx / DO, c = idx % DO;
      Bs[kk][c] = Wr[(size_t)(k0 + kk) * DO + c];
    }
    __syncthreads();
    #pragma unroll
    for (int kk = 0; kk < 16; kk++) {
      float a[8], bv[TN];
      #pragma unroll
      for (int i = 0; i < 8; i++) a[i] = As[ty * 8 + i][kk];
      #pragma unroll
      for (int j = 0; j < TN; j++) bv[j] = Bs[kk][tx * TN + j];
      #pragma unroll
      for (int i = 0; i < 8; i++)
        #pragma unroll
        for (int j = 0; j < TN; j++) acc[i][j] = fmaf(a[i], bv[j], acc[i][j]);
    }
    __syncthreads();
  }
  #pragma unroll
  for (int i = 0; i < 8; i++) {
    int row = m0 + ty * 8 + i;
    if (row < N_NODES) {
      float* yp = Y + (size_t)row * LD + r * DO + tx * TN;
      #pragma unroll
      for (int j = 0; j < TN; j += 4) {
        *(float4*)(yp + j) = make_float4(acc[i][j], acc[i][j+1], acc[i][j+2], acc[i][j+3]);
      }
    }
  }
}

// one wave per (node, 64-col chunk): chunked so the gather working set
// (N*3rel*256B = 77 MB per chunk) stays LLC-resident; edge loop unrolled x4 for MLP.
template<int DO>
__launch_bounds__(256)
__global__ void agg_kernel(const float* __restrict__ Y, const float2* __restrict__ sc,
                           const int* __restrict__ row_off,
                           const float* __restrict__ b, float* __restrict__ out, int apply_relu) {
  constexpr int LD = 3 * DO;
  int node  = blockIdx.x * 4 + ((int)threadIdx.x >> 6);
  int lane  = (int)threadIdx.x & 63;
  int col   = (int)blockIdx.y * 64 + lane;   // gridDim.y = DO/64
  if (node >= N_NODES) return;
  float acc = b[0 * DO + col] + b[1 * DO + col] + b[2 * DO + col];
  #pragma unroll
  for (int r = 0; r < N_REL; r++) {
    const int* ro = row_off + r * (N_NODES + 1);
    int beg = ro[node], end = ro[node + 1];
    const float2* scp = sc + (size_t)r * N_EDGE;
    const float*  Yr  = Y + r * DO + col;
    int e = beg;
    for (; e + 4 <= end; e += 4) {
      float2 q0 = scp[e+0], q1 = scp[e+1], q2 = scp[e+2], q3 = scp[e+3];
      int s0 = __float_as_int(q0.x), s1 = __float_as_int(q1.x);
      int s2 = __float_as_int(q2.x), s3 = __float_as_int(q3.x);
      float v0 = Yr[(size_t)s0 * LD];
      float v1 = Yr[(size_t)s1 * LD];
      float v2 = Yr[(size_t)s2 * LD];
      float v3 = Yr[(size_t)s3 * LD];
      acc = fmaf(q0.y, v0, acc);
      acc = fmaf(q1.y, v1, acc);
      acc = fmaf(q2.y, v2, acc);
      acc = fmaf(q3.y, v3, acc);
    }
    for (; e < end; e++) {
      float2 q = scp[e];
      acc = fmaf(q.y, Yr[(size_t)__float_as_int(q.x) * LD], acc);
    }
  }
  float v = acc;
  if (apply_relu) v = fmaxf(v, 0.f);
  out[(size_t)node * DO + col] = v;
}

// ---------------- launch ----------------

extern "C" void kernel_launch(void* const* d_in, const int* in_sizes, int n_in,
                              void* d_out, int out_size, void* d_ws, size_t ws_size,
                              hipStream_t stream) {
  const float* x   = (const float*)d_in[0];
  const int*   src = (const int*)d_in[1];
  const int*   dst = (const int*)d_in[2];
  const float* Wl[6]; const float* bl[6];
  for (int i = 0; i < 6; i++) { Wl[i] = (const float*)d_in[3 + 2*i]; bl[i] = (const float*)d_in[4 + 2*i]; }

  char* ws = (char*)d_ws;
  size_t off = 0;
  auto take = [&](size_t bytes) -> char* {
    char* p = ws + off;
    off = (off + bytes + 255) & ~(size_t)255;
    return p;
  };
  float*  h       = (float*)take((size_t)N_NODES * 128 * 4);
  float*  Y       = (float*)take((size_t)N_NODES * 384 * 4);
  int*    deg     = (int*)  take((size_t)2 * N_REL * N_NODES * 4);   // deg_out | deg_in
  int*    deg_out = deg;
  int*    deg_in  = deg + N_REL * N_NODES;
  float*  inv_out = (float*)take((size_t)N_REL * N_NODES * 4);
  float*  inv_in  = (float*)take((size_t)N_REL * N_NODES * 4);
  int*    row_off = (int*)  take((size_t)N_REL * (N_NODES + 1) * 4);
  int*    cursor  = (int*)  take((size_t)N_REL * N_NODES * 4);
  float2* s_sc    = (float2*)take((size_t)N_REL * N_EDGE * 8);
  (void)ws_size; (void)in_sizes; (void)n_in; (void)out_size;

  hipMemsetAsync(deg, 0, (size_t)2 * N_REL * N_NODES * 4, stream);

  const int eblocks = (N_REL * N_EDGE + 255) / 256;
  const int nblocks = (N_REL * N_NODES + 255) / 256;
  degree_kernel<<<eblocks, 256, 0, stream>>>(src, dst, deg_out, deg_in);
  inv_kernel<<<nblocks, 256, 0, stream>>>(deg_out, deg_in, inv_out, inv_in);
  scan_kernel<<<N_REL, 1024, 0, stream>>>(deg_in, row_off, cursor);
  bucket_kernel<<<eblocks, 256, 0, stream>>>(src, dst, inv_out, inv_in, cursor, s_sc);

  const int mtiles = (N_NODES + 127) / 128;
  const int agg_blocks = (N_NODES + 3) / 4;
  const float* h_in = x;
  for (int L = 0; L < 6; L++) {
    if (L < 5) {
      gemm_kernel<128><<<dim3(mtiles, 3), 256, 0, stream>>>(h_in, Wl[L], Y);
      agg_kernel<128><<<dim3(agg_blocks, 2), 256, 0, stream>>>(Y, s_sc, row_off, bl[L], h, 1);
      h_in = h;
    } else {
      gemm_kernel<64><<<dim3(mtiles, 3), 256, 0, stream>>>(h_in, Wl[L], Y);
      agg_kernel<64><<<dim3(agg_blocks, 1), 256, 0, stream>>>(Y, s_sc, row_off, bl[L], (float*)d_out, 0);
    }
  }
}